// Round 5
// baseline (961.541 us; speedup 1.0000x reference)
//
#include <hip/hip_runtime.h>

#define F_IN 144
typedef __attribute__((ext_vector_type(8))) short short8v;
typedef __attribute__((ext_vector_type(8))) unsigned short ushort8v;
typedef __attribute__((ext_vector_type(4))) float f32x4;
typedef unsigned short u16;

// ---------------- bf16 hi/lo helpers ----------------
__device__ __forceinline__ u16 bf16rn(float x) {
    union { float f; unsigned u; } a; a.f = x;
    return (u16)((a.u + 0x7FFFu + ((a.u >> 16) & 1u)) >> 16);
}
__device__ __forceinline__ float bf16tof(u16 h) {
    union { float f; unsigned u; } a; a.u = ((unsigned)h) << 16;
    return a.f;
}
__device__ __forceinline__ void gload_lds16(const u16* g, u16* s) {
    __builtin_amdgcn_global_load_lds(
        (const __attribute__((address_space(1))) void*)g,
        (__attribute__((address_space(3))) void*)s, 16, 0, 0);
}

// ---------------- utility ----------------
__global__ void zero_i32(int* __restrict__ p, int n) {
    int i = blockIdx.x * blockDim.x + threadIdx.x;
    if (i < n) p[i] = 0;
}
__global__ void zero_f32(float* __restrict__ p, int n) {
    int i = blockIdx.x * blockDim.x + threadIdx.x;
    if (i < n) p[i] = 0.f;
}
__global__ void copy_i32(const int* __restrict__ a, int* __restrict__ b, int n) {
    int i = blockIdx.x * blockDim.x + threadIdx.x;
    if (i < n) b[i] = a[i];
}
__global__ void conv_hl(const float* __restrict__ src, u16* __restrict__ dh,
                        u16* __restrict__ dl, int n) {
    int i = blockIdx.x * 256 + threadIdx.x;
    if (i < n) {
        float v = src[i];
        u16 h = bf16rn(v);
        dh[i] = h;
        dl[i] = bf16rn(v - bf16tof(h));
    }
}

// ---------------- CSR build ----------------
__global__ void count_edges(const int* __restrict__ dst, int* __restrict__ counts, int E) {
    int e = blockIdx.x * blockDim.x + threadIdx.x;
    if (e < E) atomicAdd(&counts[dst[e]], 1);
}

__global__ __launch_bounds__(1024) void scan_counts(const int* __restrict__ counts,
                                                    int* __restrict__ rowptr, int N) {
    __shared__ int part[1024];
    int t = threadIdx.x;
    int chunk = (N + 1023) >> 10;
    int beg = t * chunk;
    int end = min(beg + chunk, N);
    int s = 0;
    for (int i = beg; i < end; ++i) s += counts[i];
    part[t] = s;
    __syncthreads();
    for (int off = 1; off < 1024; off <<= 1) {
        int v = (t >= off) ? part[t - off] : 0;
        __syncthreads();
        part[t] += v;
        __syncthreads();
    }
    int run = (t == 0) ? 0 : part[t - 1];
    for (int i = beg; i < end; ++i) { rowptr[i] = run; run += counts[i]; }
    if (end == N) rowptr[N] = run;
}

__global__ void fill_edges(const int* __restrict__ src, const int* __restrict__ dst,
                           const float* __restrict__ ea, int* __restrict__ fillhead,
                           int* __restrict__ col, float* __restrict__ wv, int E) {
    int e = blockIdx.x * blockDim.x + threadIdx.x;
    if (e < E) {
        int d = dst[e];
        int pos = atomicAdd(&fillhead[d], 1);
        col[pos] = src[e];
        wv[pos]  = ea[e];
    }
}

// ---------------- aggregation: lane-split hi/lo, one wave per node ----------------
// MODE 0: out = agg (hi/lo planes). MODE 1: out = agg + root (hi/lo planes).
// MODE 2: out = agg + root (f32).
// Lanes 0-31 accumulate the hi plane, 32-63 the lo plane; one shfl_xor(32) combines.
template<int MODE>
__global__ __launch_bounds__(256) void aggregate2(
    const u16* __restrict__ Sh, const u16* __restrict__ Sl, int SS, int NC,
    const int* __restrict__ rowptr, const int* __restrict__ col,
    const float* __restrict__ wv,
    const u16* __restrict__ Rh, const u16* __restrict__ Rl,
    u16* __restrict__ Dh, u16* __restrict__ Dl, float* __restrict__ Df,
    int F, int N)
{
    int wid = (int)((blockIdx.x * 256 + threadIdx.x) >> 6);
    if (wid >= N) return;
    int lane = threadIdx.x & 63;
    int half = lane >> 5;     // 0: hi plane, 1: lo plane
    int cl   = lane & 31;     // 8-feature chunk index
    float acc[8] = {};
    int beg = rowptr[wid], end = rowptr[wid + 1];
    if (cl < NC) {
        const u16* S = half ? Sl : Sh;
        for (int e = beg; e < end; ++e) {
            float wgt = wv[e];
            ushort8v v = *(const ushort8v*)&S[(size_t)col[e] * SS + (cl << 3)];
#pragma unroll
            for (int r = 0; r < 8; ++r) acc[r] = fmaf(wgt, bf16tof(v[r]), acc[r]);
        }
        if (MODE >= 1) {
            const u16* R = half ? Rl : Rh;
            ushort8v v = *(const ushort8v*)&R[(size_t)wid * SS + (cl << 3)];
#pragma unroll
            for (int r = 0; r < 8; ++r) acc[r] += bf16tof(v[r]);
        }
    }
#pragma unroll
    for (int r = 0; r < 8; ++r) acc[r] += __shfl_xor(acc[r], 32);
    if (cl < NC) {
        if (MODE == 2) {
            float4 o = half ? make_float4(acc[4], acc[5], acc[6], acc[7])
                            : make_float4(acc[0], acc[1], acc[2], acc[3]);
            *(float4*)&Df[(size_t)wid * F + (cl << 3) + half * 4] = o;
        } else if (half == 0) {
            ushort8v o;
#pragma unroll
            for (int r = 0; r < 8; ++r) o[r] = bf16rn(acc[r]);
            *(ushort8v*)&Dh[(size_t)wid * F + (cl << 3)] = o;
        } else {
            ushort8v o;
#pragma unroll
            for (int r = 0; r < 8; ++r) {
                u16 h = bf16rn(acc[r]);
                o[r] = bf16rn(acc[r] - bf16tof(h));
            }
            *(ushort8v*)&Dl[(size_t)wid * F + (cl << 3)] = o;
        }
    }
}

// ---------------- split-bf16 MFMA GEMM, BM=128 BN=256, 512 thr / 8 waves ----------
// DUALK=true : A = [A1|A2] along K (KK=2*K1), B = [B1|B2] along K. (aggregate-first)
// DUALK=false: A = A1 (KK=K1), B rows: r<NR1 -> B1[r], else B2[r-NR1]. (transform-first)
// 3-term split product: C = Ah*Bh + Ah*Bl + Al*Bh (~fp24). Output hi/lo planes.
// LDS 48KB single-buffered; XOR chunk swizzle on global source + ds_read (G21).
#define GBM 128
#define GBN 256

template<bool DUALK>
__global__ __launch_bounds__(512) void gemm2(
    const u16* __restrict__ A1h, const u16* __restrict__ A1l,
    const u16* __restrict__ A2h, const u16* __restrict__ A2l,
    const u16* __restrict__ B1h, const u16* __restrict__ B1l,
    const u16* __restrict__ B2h, const u16* __restrict__ B2l,
    const float* __restrict__ biasA, const float* __restrict__ biasB,
    u16* __restrict__ Ch, u16* __restrict__ Cl,
    int M, int K1, int NR1, int ldc, int doRelu)
{
    __shared__ u16 lds[24576];  // Ah[4096] Al[4096] Bh[8192] Bl[8192] (u16 counts)

    const int tid = threadIdx.x;
    const int l = tid & 63, w = tid >> 6;
    const int wm = w >> 2, wn = w & 3;           // 2 x 4 wave grid, 64x64 each
    const int lane15 = l & 15, slot = l >> 4;
    const int row0 = blockIdx.x * GBM;
    const int col0 = blockIdx.y * GBN;
    const int KK = DUALK ? 2 * K1 : K1;

    // staging constants (chunk = 16B = 8 kk)
    const int ra   = tid >> 2;                      // A row 0..127
    const int cpa  = (tid & 3) ^ ((ra >> 1) & 3);   // swizzled chunk col
    const int gra  = min(row0 + ra, M - 1);
    const int rb0  = tid >> 2;                      // B rows 0..127
    const int rb1  = 128 + rb0;                     // B rows 128..255
    const int jb   = tid & 3;
    const int cpb0 = jb ^ ((rb0 >> 1) & 3);
    const int cpb1 = jb ^ ((rb1 >> 1) & 3);
    const int wbase = w << 9;                       // w*512 u16

    f32x4 acc[4][4] = {};

    for (int kk0 = 0; kk0 < KK; kk0 += 32) {
        __syncthreads();
        // ---- stage A (hi+lo) ----
        {
            int k = kk0 + (cpa << 3);
            const u16 *ph = A1h, *pl = A1l; int kk = k;
            if (DUALK && k >= K1) { ph = A2h; pl = A2l; kk = k - K1; }
            size_t go = (size_t)gra * K1 + kk;
            gload_lds16(ph + go, &lds[wbase]);
            gload_lds16(pl + go, &lds[4096 + wbase]);
        }
        // ---- stage B rows 0..127 ----
        {
            int k = kk0 + (cpb0 << 3);
            int gc = col0 + rb0;
            const u16 *ph, *pl; int kk = k; int rowb = gc;
            if (DUALK) {
                if (k >= K1) { ph = B2h; pl = B2l; kk = k - K1; } else { ph = B1h; pl = B1l; }
            } else {
                if (gc >= NR1) { ph = B2h; pl = B2l; rowb = gc - NR1; } else { ph = B1h; pl = B1l; }
            }
            size_t go = (size_t)rowb * K1 + kk;
            gload_lds16(ph + go, &lds[8192 + wbase]);
            gload_lds16(pl + go, &lds[16384 + wbase]);
        }
        // ---- stage B rows 128..255 ----
        {
            int k = kk0 + (cpb1 << 3);
            int gc = col0 + rb1;
            const u16 *ph, *pl; int kk = k; int rowb = gc;
            if (DUALK) {
                if (k >= K1) { ph = B2h; pl = B2l; kk = k - K1; } else { ph = B1h; pl = B1l; }
            } else {
                if (gc >= NR1) { ph = B2h; pl = B2l; rowb = gc - NR1; } else { ph = B1h; pl = B1l; }
            }
            size_t go = (size_t)rowb * K1 + kk;
            gload_lds16(ph + go, &lds[8192 + 4096 + wbase]);
            gload_lds16(pl + go, &lds[16384 + 4096 + wbase]);
        }
        __syncthreads();

        // ---- fragments: B cached in regs, A streamed ----
        short8v bh[4], bl[4];
#pragma unroll
        for (int bj = 0; bj < 4; ++bj) {
            int c = wn * 64 + bj * 16 + lane15;
            int j = slot ^ ((c >> 1) & 3);
            bh[bj] = *(const short8v*)&lds[8192 + c * 32 + j * 8];
            bl[bj] = *(const short8v*)&lds[16384 + c * 32 + j * 8];
        }
#pragma unroll
        for (int bi = 0; bi < 4; ++bi) {
            int r = wm * 64 + bi * 16 + lane15;
            int j = slot ^ ((r >> 1) & 3);
            short8v ah = *(const short8v*)&lds[r * 32 + j * 8];
            short8v al = *(const short8v*)&lds[4096 + r * 32 + j * 8];
#pragma unroll
            for (int bj = 0; bj < 4; ++bj) {
                acc[bi][bj] = __builtin_amdgcn_mfma_f32_16x16x32_bf16(ah, bh[bj], acc[bi][bj], 0, 0, 0);
                acc[bi][bj] = __builtin_amdgcn_mfma_f32_16x16x32_bf16(ah, bl[bj], acc[bi][bj], 0, 0, 0);
                acc[bi][bj] = __builtin_amdgcn_mfma_f32_16x16x32_bf16(al, bh[bj], acc[bi][bj], 0, 0, 0);
            }
        }
    }

    // ---- epilogue: C/D layout col=lane&15, row=slot*4+q ----
#pragma unroll
    for (int bj = 0; bj < 4; ++bj) {
        int cc = col0 + wn * 64 + bj * 16 + lane15;
        float bv = (cc < NR1) ? (biasA ? biasA[cc] : 0.f)
                              : (biasB ? biasB[cc - NR1] : 0.f);
#pragma unroll
        for (int bi = 0; bi < 4; ++bi) {
            int rbase = row0 + wm * 64 + bi * 16 + slot * 4;
#pragma unroll
            for (int q = 0; q < 4; ++q) {
                int rr = rbase + q;
                if (rr < M) {
                    float o = acc[bi][bj][q] + bv;
                    if (doRelu) o = fmaxf(o, 0.f);
                    u16 h = bf16rn(o);
                    Ch[(size_t)rr * ldc + cc] = h;
                    Cl[(size_t)rr * ldc + cc] = bf16rn(o - bf16tof(h));
                }
            }
        }
    }
}

// ---------------- GraphNorm (F = 256) on hi/lo storage ----------------
__global__ __launch_bounds__(256) void colstats_hl(const u16* __restrict__ Hh,
                                                   const u16* __restrict__ Hl,
                                                   float* __restrict__ sums,
                                                   float* __restrict__ sqs, int N) {
    int f = threadIdx.x;
    float s = 0.f, q = 0.f;
    for (int i = blockIdx.x; i < N; i += gridDim.x) {
        float v = bf16tof(Hh[(size_t)i * 256 + f]) + bf16tof(Hl[(size_t)i * 256 + f]);
        s += v;
        q = fmaf(v, v, q);
    }
    atomicAdd(&sums[f], s);
    atomicAdd(&sqs[f], q);
}

__global__ void norm_prep(const float* __restrict__ sums, const float* __restrict__ sqs,
                          const float* __restrict__ gw, const float* __restrict__ gb,
                          const float* __restrict__ gms, float* __restrict__ scaleF,
                          float* __restrict__ shiftF, float invN) {
    int f = threadIdx.x;  // 256 threads
    float mu  = sums[f] * invN;
    float ex2 = sqs[f] * invN;
    float a   = gms[f] * mu;
    float var = ex2 - 2.f * a * mu + a * a;
    float inv = rsqrtf(var + 1e-5f);
    float sc  = gw[f] * inv;
    scaleF[f] = sc;
    shiftF[f] = gb[f] - a * sc;
}

__global__ __launch_bounds__(256) void norm_apply_hl(
    ushort4* __restrict__ Hh, ushort4* __restrict__ Hl,
    const float4* __restrict__ scaleF, const float4* __restrict__ shiftF, int n4) {
    int i = blockIdx.x * 256 + threadIdx.x;
    if (i >= n4) return;
    int f4 = i & 63;
    ushort4 h = Hh[i], lo = Hl[i];
    float4 sc = scaleF[f4], sh = shiftF[f4];
    float vx = fmaxf(fmaf(bf16tof(h.x) + bf16tof(lo.x), sc.x, sh.x), 0.f);
    float vy = fmaxf(fmaf(bf16tof(h.y) + bf16tof(lo.y), sc.y, sh.y), 0.f);
    float vz = fmaxf(fmaf(bf16tof(h.z) + bf16tof(lo.z), sc.z, sh.z), 0.f);
    float vw = fmaxf(fmaf(bf16tof(h.w) + bf16tof(lo.w), sc.w, sh.w), 0.f);
    ushort4 oh, ol;
    oh.x = bf16rn(vx); ol.x = bf16rn(vx - bf16tof(oh.x));
    oh.y = bf16rn(vy); ol.y = bf16rn(vy - bf16tof(oh.y));
    oh.z = bf16rn(vz); ol.z = bf16rn(vz - bf16tof(oh.z));
    oh.w = bf16rn(vw); ol.w = bf16rn(vw - bf16tof(oh.w));
    Hh[i] = oh;
    Hl[i] = ol;
}

// ---------------- launch ----------------
extern "C" void kernel_launch(void* const* d_in, const int* in_sizes, int n_in,
                              void* d_out, int out_size, void* d_ws, size_t ws_size,
                              hipStream_t stream) {
    const float* x   = (const float*)d_in[0];
    const int*   ei  = (const int*)d_in[1];
    const float* ea  = (const float*)d_in[2];
    const float* Wr1 = (const float*)d_in[3];
    const float* b1  = (const float*)d_in[4];
    const float* Wo1 = (const float*)d_in[5];
    const float* Wr2 = (const float*)d_in[6];
    const float* b2  = (const float*)d_in[7];
    const float* Wo2 = (const float*)d_in[8];
    const float* Wr3 = (const float*)d_in[9];
    const float* b3  = (const float*)d_in[10];
    const float* Wo3 = (const float*)d_in[11];
    const float* Wr4 = (const float*)d_in[12];
    const float* b4  = (const float*)d_in[13];
    const float* Wo4 = (const float*)d_in[14];
    const float* gw  = (const float*)d_in[15];
    const float* gb  = (const float*)d_in[16];
    const float* gms = (const float*)d_in[17];

    const int Nn = in_sizes[0] / F_IN;   // 50000
    const int E  = in_sizes[1] / 2;      // 400000
    const int* src = ei;
    const int* dst = ei + E;

    char* wp = (char*)d_ws;
    auto alloc = [&](size_t bytes) -> void* {
        void* p = (void*)wp;
        wp += (bytes + 255) & ~(size_t)255;
        return p;
    };
    int*   counts   = (int*)alloc((size_t)Nn * 4);
    int*   rowptr   = (int*)alloc((size_t)(Nn + 1) * 4);
    int*   fillhead = (int*)alloc((size_t)Nn * 4);
    int*   col      = (int*)alloc((size_t)E * 4);
    float* wv       = (float*)alloc((size_t)E * 4);
    float* stats    = (float*)alloc(1024 * 4);
    float* sums = stats, *sqs = stats + 256, *scaleF = stats + 512, *shiftF = stats + 768;
    // weights hi/lo
    u16* wr1h = (u16*)alloc(2u * 256 * 144); u16* wr1l = (u16*)alloc(2u * 256 * 144);
    u16* wo1h = (u16*)alloc(2u * 256 * 144); u16* wo1l = (u16*)alloc(2u * 256 * 144);
    u16* wr2h = (u16*)alloc(2u * 512 * 256); u16* wr2l = (u16*)alloc(2u * 512 * 256);
    u16* wo2h = (u16*)alloc(2u * 512 * 256); u16* wo2l = (u16*)alloc(2u * 512 * 256);
    u16* wr3h = (u16*)alloc(2u * 256 * 512); u16* wr3l = (u16*)alloc(2u * 256 * 512);
    u16* wo3h = (u16*)alloc(2u * 256 * 512); u16* wo3l = (u16*)alloc(2u * 256 * 512);
    u16* wr4h = (u16*)alloc(2u * 128 * 256); u16* wr4l = (u16*)alloc(2u * 128 * 256);
    u16* wo4h = (u16*)alloc(2u * 128 * 256); u16* wo4l = (u16*)alloc(2u * 128 * 256);

    // ---- single lifetime-packed big region (u16 units), total Nn*2336*2 B = 233.6 MB ----
    // live layout:  X[0, 288) | AGG[288, 800) | H1[800, 1312) | H2[1312, 2336)   (per node)
    // reuse:        Y3 -> [0, 1024)  (X+AGG+H1 dead after GEMM2)
    //               H3 -> [1312, 1824) (H2 dead after GEMM3)
    //               Y4 -> [0, 512)   (Y3 dead after L3 aggregate)
    u16* big = (u16*)alloc((size_t)Nn * 2336 * 2);
    const size_t NS = (size_t)Nn;
    u16* Xh  = big;               u16* Xl  = big + NS * 144;
    u16* AGh = big + NS * 288;    u16* AGl = big + NS * 544;
    u16* H1h = big + NS * 800;    u16* H1l = big + NS * 1056;
    u16* H2h = big + NS * 1312;   u16* H2l = big + NS * 1824;
    u16* Y3h = big;               u16* Y3l = big + NS * 512;
    u16* H3h = big + NS * 1312;   u16* H3l = big + NS * 1568;
    u16* Y4h = big;               u16* Y4l = big + NS * 256;

    const int TB = 256;
    // CSR build
    zero_i32<<<(Nn + TB - 1) / TB, TB, 0, stream>>>(counts, Nn);
    count_edges<<<(E + TB - 1) / TB, TB, 0, stream>>>(dst, counts, E);
    scan_counts<<<1, 1024, 0, stream>>>(counts, rowptr, Nn);
    copy_i32<<<(Nn + TB - 1) / TB, TB, 0, stream>>>(rowptr, fillhead, Nn);
    fill_edges<<<(E + TB - 1) / TB, TB, 0, stream>>>(src, dst, ea, fillhead, col, wv, E);

    // conversions
    int nx = Nn * F_IN;
    conv_hl<<<(nx + 255) / 256, 256, 0, stream>>>(x, Xh, Xl, nx);
    struct WC { const float* s; u16* h; u16* l; int n; } wc[8] = {
        {Wr1, wr1h, wr1l, 256 * 144}, {Wo1, wo1h, wo1l, 256 * 144},
        {Wr2, wr2h, wr2l, 512 * 256}, {Wo2, wo2h, wo2l, 512 * 256},
        {Wr3, wr3h, wr3l, 256 * 512}, {Wo3, wo3h, wo3l, 256 * 512},
        {Wr4, wr4h, wr4l, 128 * 256}, {Wo4, wo4h, wo4l, 128 * 256}};
    for (int i = 0; i < 8; ++i)
        conv_hl<<<(wc[i].n + 255) / 256, 256, 0, stream>>>(wc[i].s, wc[i].h, wc[i].l, wc[i].n);

    int aggGrid = (Nn + 3) / 4;
    int mB = (Nn + GBM - 1) / GBM;  // 391

    // Layer 1 (aggregate-first): agg(x) ; [agg|x] * [Wr1|Wo1]^T + b1, relu -> H1
    aggregate2<0><<<aggGrid, TB, 0, stream>>>(Xh, Xl, 144, 18, rowptr, col, wv,
                                              nullptr, nullptr, AGh, AGl, nullptr, 144, Nn);
    gemm2<true><<<dim3(mB, 1), 512, 0, stream>>>(AGh, AGl, Xh, Xl,
                                                 wr1h, wr1l, wo1h, wo1l,
                                                 b1, nullptr, H1h, H1l,
                                                 Nn, 144, 256, 256, 1);
    // Layer 2 (aggregate-first): 256 -> 512, relu -> H2
    aggregate2<0><<<aggGrid, TB, 0, stream>>>(H1h, H1l, 256, 32, rowptr, col, wv,
                                              nullptr, nullptr, AGh, AGl, nullptr, 256, Nn);
    gemm2<true><<<dim3(mB, 2), 512, 0, stream>>>(AGh, AGl, H1h, H1l,
                                                 wr2h, wr2l, wo2h, wo2l,
                                                 b2, nullptr, H2h, H2l,
                                                 Nn, 256, 512, 512, 1);
    // Layer 3 (transform-first): Y3 = [H2*Wr3^T, H2*Wo3^T + b3]; H3 = agg(Yrel)+Yroot
    gemm2<false><<<dim3(mB, 2), 512, 0, stream>>>(H2h, H2l, H2h, H2l,
                                                  wr3h, wr3l, wo3h, wo3l,
                                                  nullptr, b3, Y3h, Y3l,
                                                  Nn, 512, 256, 512, 0);
    aggregate2<1><<<aggGrid, TB, 0, stream>>>(Y3h, Y3l, 512, 32, rowptr, col, wv,
                                              Y3h + 256, Y3l + 256, H3h, H3l, nullptr, 256, Nn);
    // GraphNorm + relu in place on H3
    zero_f32<<<2, TB, 0, stream>>>(stats, 512);
    colstats_hl<<<256, TB, 0, stream>>>(H3h, H3l, sums, sqs, Nn);
    norm_prep<<<1, 256, 0, stream>>>(sums, sqs, gw, gb, gms, scaleF, shiftF, 1.0f / Nn);
    norm_apply_hl<<<(Nn * 64 + TB - 1) / TB, TB, 0, stream>>>(
        (ushort4*)H3h, (ushort4*)H3l, (const float4*)scaleF, (const float4*)shiftF, Nn * 64);
    // Layer 4 (transform-first): Y4 = [H3*Wr4^T, H3*Wo4^T + b4]; out = agg(Yrel)+Yroot (f32)
    gemm2<false><<<dim3(mB, 1), 512, 0, stream>>>(H3h, H3l, H3h, H3l,
                                                  wr4h, wr4l, wo4h, wo4l,
                                                  nullptr, b4, Y4h, Y4l,
                                                  Nn, 256, 128, 256, 0);
    aggregate2<2><<<aggGrid, TB, 0, stream>>>(Y4h, Y4l, 256, 16, rowptr, col, wv,
                                              Y4h + 128, Y4l + 128, nullptr, nullptr,
                                              (float*)d_out, 128, Nn);
}